// Round 1
// baseline (629.977 us; speedup 1.0000x reference)
//
#include <hip/hip_runtime.h>
#include <math.h>

// Problem constants (from reference setup_inputs): B=64, N=512, d=64
#define NB 64
#define NN 512
#define ND 64

#define BIGV 1e10f   // reference replaces inf with 1e10 inside softmin

// ---------------------------------------------------------------------------
// Kernel 1: D[b][i][j] = || X[b][i][:] - Y[b][j][:] ||_2
// Tiled 32x32 per block, LDS-staged, 256 threads, 4 outputs/thread.
// ---------------------------------------------------------------------------
__global__ __launch_bounds__(256) void cdist_kernel(const float* __restrict__ X,
                                                    const float* __restrict__ Y,
                                                    float* __restrict__ D) {
    __shared__ float Xs[32][ND + 1];  // +1 pad: kills stride-64 bank conflicts
    __shared__ float Ys[32][ND + 1];

    const int b  = blockIdx.z;
    const int i0 = blockIdx.y * 32;
    const int j0 = blockIdx.x * 32;
    const int t  = threadIdx.x;

    // Stage 32x64 tiles of X and Y (contiguous rows) as float4: 512 f4 each.
    const float4* Xg = (const float4*)(X + ((size_t)b * NN + i0) * ND);
    const float4* Yg = (const float4*)(Y + ((size_t)b * NN + j0) * ND);
    #pragma unroll
    for (int l = t; l < 512; l += 256) {
        const int row = l >> 4;
        const int c4  = (l & 15) * 4;
        float4 v = Xg[l];
        Xs[row][c4 + 0] = v.x; Xs[row][c4 + 1] = v.y;
        Xs[row][c4 + 2] = v.z; Xs[row][c4 + 3] = v.w;
        float4 w = Yg[l];
        Ys[row][c4 + 0] = w.x; Ys[row][c4 + 1] = w.y;
        Ys[row][c4 + 2] = w.z; Ys[row][c4 + 3] = w.w;
    }
    __syncthreads();

    const int tx = t & 31;   // j within tile
    const int ty = t >> 5;   // base i within tile (rows ty, ty+8, ty+16, ty+24)

    float a0 = 0.f, a1 = 0.f, a2 = 0.f, a3 = 0.f;
    #pragma unroll
    for (int k = 0; k < ND; ++k) {
        const float y = Ys[tx][k];
        float d0 = Xs[ty     ][k] - y; a0 += d0 * d0;
        float d1 = Xs[ty +  8][k] - y; a1 += d1 * d1;
        float d2 = Xs[ty + 16][k] - y; a2 += d2 * d2;
        float d3 = Xs[ty + 24][k] - y; a3 += d3 * d3;
    }

    float* Dp = D + ((size_t)b * NN + i0) * NN + j0;
    Dp[(ty     ) * NN + tx] = sqrtf(a0);
    Dp[(ty +  8) * NN + tx] = sqrtf(a1);
    Dp[(ty + 16) * NN + tx] = sqrtf(a2);
    Dp[(ty + 24) * NN + tx] = sqrtf(a3);
}

// ---------------------------------------------------------------------------
// Kernel 2: soft-DTW DP, one block per batch, wavefront over anti-diagonals.
// R[i][j] = D[i-1][j-1] + softmin(R[i-1][j-1], R[i-1][j], R[i][j-1])
// Three rotating diagonal buffers in LDS; buf[s%3][i] = R[i][s-i].
// Boundaries R[0][*]=R[*][0]=inf stored as 1e10 (matches reference's
// inf->1e10 replacement: exp(-1e10) underflows to 0 exactly).
// ---------------------------------------------------------------------------
__global__ __launch_bounds__(512) void dtw_kernel(const float* __restrict__ D,
                                                  float* __restrict__ out) {
    __shared__ float R[3][NN + 1];

    const int b   = blockIdx.x;
    const int tid = threadIdx.x;
    const float* __restrict__ Db = D + (size_t)b * NN * NN;

    if (tid == 0) {
        R[0][0] = 0.0f;   // R[0][0]
        R[1][0] = BIGV;   // R[0][1]
        R[1][1] = BIGV;   // R[1][0]
    }
    __syncthreads();

    const int i = tid + 1;  // this thread owns DP row i for the whole sweep

    for (int s = 2; s <= 2 * NN; ++s) {
        const int cur = s % 3;
        const int m1  = (s - 1) % 3;
        const int m2  = (s - 2) % 3;
        const int ilo = (s - NN > 1) ? (s - NN) : 1;
        const int ihi = (NN < s - 1) ? NN : (s - 1);

        if (i >= ilo && i <= ihi) {
            const int j = s - i;                       // 1..N
            const float d  = Db[(i - 1) * NN + (j - 1)];
            const float dg = R[m2][i - 1];             // R[i-1][j-1]
            const float up = R[m1][i - 1];             // R[i-1][j]
            const float lf = R[m1][i];                 // R[i][j-1]
            const float m  = fminf(dg, fminf(up, lf));
            const float sum = __expf(m - dg) + __expf(m - up) + __expf(m - lf);
            R[cur][i] = d + m - __logf(sum);
        }
        if (tid == 0) {
            R[cur][0] = BIGV;                 // R[0][s]
            if (s <= NN) R[cur][s] = BIGV;    // R[s][0]
        }
        __syncthreads();
    }

    if (tid == 0) out[b] = R[(2 * NN) % 3][NN];  // R[N][N]
}

extern "C" void kernel_launch(void* const* d_in, const int* in_sizes, int n_in,
                              void* d_out, int out_size, void* d_ws, size_t ws_size,
                              hipStream_t stream) {
    const float* X = (const float*)d_in[0];
    const float* Y = (const float*)d_in[1];
    float* out = (float*)d_out;
    float* D   = (float*)d_ws;   // 64*512*512*4 = 64 MB scratch

    cdist_kernel<<<dim3(NN / 32, NN / 32, NB), 256, 0, stream>>>(X, Y, D);
    dtw_kernel<<<NB, NN, 0, stream>>>(D, out);
}

// Round 2
// 314.169 us; speedup vs baseline: 2.0052x; 2.0052x over previous
//
#include <hip/hip_runtime.h>
#include <math.h>

// Problem constants: B=64, N=512, d=64
#define NB 64
#define NN 512
#define ND 64

#define BIGV  1.0e10f                 // reference replaces inf with 1e10
#define LOG2E 1.4426950408889634f
#define LN2   0.6931471805599453f

// ---------------------------------------------------------------------------
// Kernel 1: Dt[b][j][i] = || X[b][i][:] - Y[b][j][:] ||_2 * LOG2E
// (transposed + pre-scaled for the base-2 DP kernel).
// 32x32 tile, float4 LDS reads, 256 threads, 4 outputs/thread.
// ---------------------------------------------------------------------------
__global__ __launch_bounds__(256) void cdist_kernel(const float* __restrict__ X,
                                                    const float* __restrict__ Y,
                                                    float* __restrict__ Dt) {
    __shared__ float Xs[32][ND + 4];  // stride 68 floats: 16B-aligned rows
    __shared__ float Ys[32][ND + 4];

    const int b  = blockIdx.z;
    const int i0 = blockIdx.x * 32;   // X-row block (inner output dim)
    const int j0 = blockIdx.y * 32;   // Y-row block (outer output dim)
    const int t  = threadIdx.x;

    const float4* Xg = (const float4*)(X + ((size_t)b * NN + i0) * ND);
    const float4* Yg = (const float4*)(Y + ((size_t)b * NN + j0) * ND);
    #pragma unroll
    for (int l = t; l < 512; l += 256) {
        const int row = l >> 4;
        const int c4  = (l & 15) * 4;
        float4 v = Xg[l];
        *(float4*)&Xs[row][c4] = v;
        float4 w = Yg[l];
        *(float4*)&Ys[row][c4] = w;
    }
    __syncthreads();

    const int tx = t & 31;   // i within tile (lane-varying)
    const int ty = t >> 5;   // j base within tile (rows ty, ty+8, ty+16, ty+24)

    float a0 = 0.f, a1 = 0.f, a2 = 0.f, a3 = 0.f;
    #pragma unroll
    for (int k = 0; k < ND; k += 4) {
        const float4 xv = *(const float4*)&Xs[tx][k];
        float4 yv;
        float d;
        yv = *(const float4*)&Ys[ty][k];
        d = yv.x - xv.x; a0 += d * d;  d = yv.y - xv.y; a0 += d * d;
        d = yv.z - xv.z; a0 += d * d;  d = yv.w - xv.w; a0 += d * d;
        yv = *(const float4*)&Ys[ty + 8][k];
        d = yv.x - xv.x; a1 += d * d;  d = yv.y - xv.y; a1 += d * d;
        d = yv.z - xv.z; a1 += d * d;  d = yv.w - xv.w; a1 += d * d;
        yv = *(const float4*)&Ys[ty + 16][k];
        d = yv.x - xv.x; a2 += d * d;  d = yv.y - xv.y; a2 += d * d;
        d = yv.z - xv.z; a2 += d * d;  d = yv.w - xv.w; a2 += d * d;
        yv = *(const float4*)&Ys[ty + 24][k];
        d = yv.x - xv.x; a3 += d * d;  d = yv.y - xv.y; a3 += d * d;
        d = yv.z - xv.z; a3 += d * d;  d = yv.w - xv.w; a3 += d * d;
    }

    // Dt[b][j][i], i = i0+tx consecutive -> coalesced
    float* Dp = Dt + ((size_t)b * NN + j0) * NN + i0 + tx;
    Dp[(ty     ) * NN] = sqrtf(a0) * LOG2E;
    Dp[(ty +  8) * NN] = sqrtf(a1) * LOG2E;
    Dp[(ty + 16) * NN] = sqrtf(a2) * LOG2E;
    Dp[(ty + 24) * NN] = sqrtf(a3) * LOG2E;
}

// ---------------------------------------------------------------------------
// Kernel 2: soft-DTW DP, one WAVE per batch, barrier-free.
// Lane t owns DP rows 8t+1..8t+8; lanes skewed by one column; neighbor row
// values passed with __shfl_up (wave-lockstep => no __syncthreads at all).
// Works in base-2-scaled domain: R_s = R*log2(e), so
//   r_s = d_s + m_s - log2( sum 2^(m_s - x_s) )   (no mul by 1/ln2 anywhere)
// min term contributes exactly 1 => only 2 exp2 via med3/max3.
// ---------------------------------------------------------------------------
__global__ __launch_bounds__(64) void dtw_kernel(const float* __restrict__ Dt,
                                                 float* __restrict__ out) {
    const int b = blockIdx.x;
    const int t = threadIdx.x;                 // lane 0..63
    const float* __restrict__ Db = Dt + (size_t)b * NN * NN;
    const int ib = 8 * t;                      // first owned row - 1 (0-indexed D row)

    float left[8];                             // R[ib+1..ib+8][j-1] (scaled)
    #pragma unroll
    for (int k = 0; k < 8; ++k) left[k] = BIGV;

    float topU   = (t == 0) ? 0.0f : BIGV;     // becomes topL=R[0][0]=0 at ss=0
    float bottom = BIGV;                       // last-row value passed downward

    // prefetch column j=1: Dt[0][ib..ib+7]
    float4 nx0 = *(const float4*)(Db + ib);
    float4 nx1 = *(const float4*)(Db + ib + 4);

    for (int ss = 0; ss < NN + 63; ++ss) {
        const float recv = __shfl_up(bottom, 1);
        const float topL = topU;               // R[ib][j-1]
        topU = (t == 0) ? BIGV : recv;         // R[ib][j]

        const int j = ss - t + 1;
        const float4 c0 = nx0, c1 = nx1;

        const int jn = j + 1;                  // prefetch next column
        if (jn >= 1 && jn <= NN) {
            const float* p = Db + (size_t)(jn - 1) * NN + ib;
            nx0 = *(const float4*)(p);
            nx1 = *(const float4*)(p + 4);
        }

        if (j >= 1 && j <= NN) {
            float up = topU, diag = topL;
            float d0 = c0.x, d1 = c0.y, d2 = c0.z, d3 = c0.w;
            float d4 = c1.x, d5 = c1.y, d6 = c1.z, d7 = c1.w;
            const float dd[8] = {d0, d1, d2, d3, d4, d5, d6, d7};
            #pragma unroll
            for (int k = 0; k < 8; ++k) {
                const float lf = left[k];
                const float m  = fminf(diag, fminf(up, lf));
                const float M  = fmaxf(diag, fmaxf(up, lf));
                const float md = __builtin_amdgcn_fmed3f(diag, up, lf);
                const float S  = 1.0f + __builtin_amdgcn_exp2f(m - md)
                                      + __builtin_amdgcn_exp2f(m - M);
                const float r  = dd[k] + m - __builtin_amdgcn_logf(S); // logf = log2 HW op
                diag    = lf;
                left[k] = r;
                up      = r;
            }
            bottom = up;
        }
    }

    if (t == 63) out[b] = left[7] * LN2;       // R[N][N], unscaled
}

extern "C" void kernel_launch(void* const* d_in, const int* in_sizes, int n_in,
                              void* d_out, int out_size, void* d_ws, size_t ws_size,
                              hipStream_t stream) {
    const float* X = (const float*)d_in[0];
    const float* Y = (const float*)d_in[1];
    float* out = (float*)d_out;
    float* Dt  = (float*)d_ws;   // 64*512*512*4 = 64 MB scratch (transposed D)

    cdist_kernel<<<dim3(NN / 32, NN / 32, NB), 256, 0, stream>>>(X, Y, Dt);
    dtw_kernel<<<NB, 64, 0, stream>>>(Dt, out);
}

// Round 3
// 298.880 us; speedup vs baseline: 2.1078x; 1.0512x over previous
//
#include <hip/hip_runtime.h>
#include <math.h>

// Problem constants: B=64, N=512, d=64
#define NB 64
#define NN 512
#define ND 64

#define BIGV  1.0e10f                 // reference replaces inf with 1e10
#define LOG2E 1.4426950408889634f
#define LN2   0.6931471805599453f

typedef __attribute__((ext_vector_type(8))) short  bf16x8;  // 8 bf16 in 4 VGPRs
typedef __attribute__((ext_vector_type(4))) float  f32x4;

// fp32 -> bf16 bits, round-to-nearest-even (inputs are finite)
static __device__ __forceinline__ short f2bf(float f) {
    unsigned u = __float_as_uint(f);
    u += 0x7FFFu + ((u >> 16) & 1u);
    return (short)(u >> 16);
}

// ---------------------------------------------------------------------------
// Kernel 1 (MFMA): Dt[b][j][i] = ||X[b][i]-Y[b][j]||_2 * LOG2E
//   = sqrt(max(nx[i]+ny[j]-2*(x.y),0)) * LOG2E
// Block: 256 thr = 4 waves in 2x2; each wave computes a 64x64 tile of the
// 128x128 block tile. A-operand = Y rows (m=j), B-operand = X rows (n=i) so
// the C/D fast dim (lane&15) is i -> coalesced transposed store.
// MFMA 16x16x32 bf16 layouts (HW-verified per guide):
//   A[m][k]: lane = quad*16+m, elems k = quad*8+jj ;  B symmetric (n=lane&15)
//   C/D:     col(n) = lane&15, row(m) = quad*4+reg
// ---------------------------------------------------------------------------
__global__ __launch_bounds__(256) void cdist_kernel(const float* __restrict__ X,
                                                    const float* __restrict__ Y,
                                                    float* __restrict__ Dt) {
    __shared__ float nxs[128];   // |X row|^2 for this block's i-range
    __shared__ float nys[128];   // |Y row|^2 for this block's j-range

    const int b  = blockIdx.z;
    const int ib = blockIdx.x * 128;   // i base (X rows)
    const int jb = blockIdx.y * 128;   // j base (Y rows)
    const int t  = threadIdx.x;

    // --- block-cooperative row norms (one thread per row, fp32 exact) ---
    {
        const int r = t & 127;
        const float* src = (t < 128)
            ? (X + ((size_t)b * NN + ib + r) * ND)
            : (Y + ((size_t)b * NN + jb + r) * ND);
        float s = 0.f;
        #pragma unroll
        for (int k = 0; k < ND; k += 4) {
            float4 v = *(const float4*)(src + k);
            s += v.x * v.x + v.y * v.y + v.z * v.z + v.w * v.w;
        }
        if (t < 128) nxs[r] = s; else nys[r] = s;
    }
    __syncthreads();

    const int wave = t >> 6;
    const int wi   = (wave & 1) * 64;   // i offset of this wave's 64x64 tile
    const int wj   = (wave >> 1) * 64;  // j offset
    const int lane = t & 63;
    const int lm   = lane & 15;
    const int quad = lane >> 4;

    f32x4 acc[4][4];
    #pragma unroll
    for (int mt = 0; mt < 4; ++mt)
        #pragma unroll
        for (int nt = 0; nt < 4; ++nt)
            acc[mt][nt] = (f32x4){0.f, 0.f, 0.f, 0.f};

    #pragma unroll
    for (int h = 0; h < 2; ++h) {
        bf16x8 Af[4], Bf[4];
        #pragma unroll
        for (int mt = 0; mt < 4; ++mt) {         // A from Y rows (m = j dim)
            const float* p = Y + ((size_t)b * NN + jb + wj + mt * 16 + lm) * ND
                               + h * 32 + quad * 8;
            float4 v0 = *(const float4*)p;
            float4 v1 = *(const float4*)(p + 4);
            bf16x8 a;
            a[0] = f2bf(v0.x); a[1] = f2bf(v0.y); a[2] = f2bf(v0.z); a[3] = f2bf(v0.w);
            a[4] = f2bf(v1.x); a[5] = f2bf(v1.y); a[6] = f2bf(v1.z); a[7] = f2bf(v1.w);
            Af[mt] = a;
        }
        #pragma unroll
        for (int nt = 0; nt < 4; ++nt) {         // B from X rows (n = i dim)
            const float* p = X + ((size_t)b * NN + ib + wi + nt * 16 + lm) * ND
                               + h * 32 + quad * 8;
            float4 v0 = *(const float4*)p;
            float4 v1 = *(const float4*)(p + 4);
            bf16x8 a;
            a[0] = f2bf(v0.x); a[1] = f2bf(v0.y); a[2] = f2bf(v0.z); a[3] = f2bf(v0.w);
            a[4] = f2bf(v1.x); a[5] = f2bf(v1.y); a[6] = f2bf(v1.z); a[7] = f2bf(v1.w);
            Bf[nt] = a;
        }
        #pragma unroll
        for (int mt = 0; mt < 4; ++mt)
            #pragma unroll
            for (int nt = 0; nt < 4; ++nt)
                acc[mt][nt] = __builtin_amdgcn_mfma_f32_16x16x32_bf16(
                    Af[mt], Bf[nt], acc[mt][nt], 0, 0, 0);
    }

    // --- epilogue: d2 = ny[j] + nx[i] - 2*s; Dt[b][j][i] = sqrt(max(d2,0))*LOG2E
    float nxv[4], nyv[4][4];
    #pragma unroll
    for (int nt = 0; nt < 4; ++nt) nxv[nt] = nxs[wi + nt * 16 + lm];
    #pragma unroll
    for (int mt = 0; mt < 4; ++mt)
        #pragma unroll
        for (int r = 0; r < 4; ++r) nyv[mt][r] = nys[wj + mt * 16 + quad * 4 + r];

    #pragma unroll
    for (int mt = 0; mt < 4; ++mt) {
        const int j = jb + wj + mt * 16 + quad * 4;
        float* Drow = Dt + ((size_t)b * NN + j) * NN + ib + wi + lm;
        #pragma unroll
        for (int r = 0; r < 4; ++r) {
            #pragma unroll
            for (int nt = 0; nt < 4; ++nt) {
                float d2 = nyv[mt][r] + nxv[nt] - 2.0f * acc[mt][nt][r];
                Drow[(size_t)r * NN + nt * 16] = sqrtf(fmaxf(d2, 0.f)) * LOG2E;
            }
        }
    }
}

// ---------------------------------------------------------------------------
// Kernel 2: soft-DTW DP, one WAVE per batch, barrier-free.
// Lane t owns DP rows 8t+1..8t+8; lanes skewed by one column. Neighbor pass
// via DPP wave_shr:1 (lane i <- lane i-1; lane 0 <- old = BIGV). Depth-3
// register prefetch ring hides L3/HBM latency on the column loads.
// Base-2 domain: r = d + m - log2(1 + 2^(m-med) + 2^(m-max)).
// ---------------------------------------------------------------------------
__global__ __launch_bounds__(64) void dtw_kernel(const float* __restrict__ Dt,
                                                 float* __restrict__ out) {
    const int b = blockIdx.x;
    const int t = threadIdx.x;                 // lane 0..63
    const float* __restrict__ Db = Dt + (size_t)b * NN * NN;
    const int ib = 8 * t;                      // first owned D-row

    float left[8];
    #pragma unroll
    for (int k = 0; k < 8; ++k) left[k] = BIGV;

    float topU   = (t == 0) ? 0.0f : BIGV;     // becomes diag R[0][0]=0 at ss=0
    float bottom = BIGV;

    // prefetch ring holding columns j, j+1, j+2 (init: cols 1..3)
    float4 f0a = *(const float4*)(Db + 0 * NN + ib);
    float4 f0b = *(const float4*)(Db + 0 * NN + ib + 4);
    float4 f1a = *(const float4*)(Db + 1 * NN + ib);
    float4 f1b = *(const float4*)(Db + 1 * NN + ib + 4);
    float4 f2a = *(const float4*)(Db + 2 * NN + ib);
    float4 f2b = *(const float4*)(Db + 2 * NN + ib + 4);

    for (int ss = 0; ss < NN + 63; ++ss) {
        // lane t receives lane t-1's bottom (prev step); lane 0 receives BIGV
        const float recv = __int_as_float(__builtin_amdgcn_update_dpp(
            __float_as_int(BIGV), __float_as_int(bottom),
            0x138 /*wave_shr:1*/, 0xf, 0xf, false));
        const float topL = topU;               // R[ib][j-1]
        topU = recv;                           // R[ib][j]

        const int j = ss - t + 1;
        const float4 c0 = f0a, c1 = f0b;
        f0a = f1a; f0b = f1b; f1a = f2a; f1b = f2b;

        const int jn = j + 3;                  // refill ring 3 columns ahead
        if (jn >= 1 && jn <= NN) {
            const float* p = Db + (size_t)(jn - 1) * NN + ib;
            f2a = *(const float4*)(p);
            f2b = *(const float4*)(p + 4);
        }

        if (j >= 1 && j <= NN) {
            float up = topU, diag = topL;
            const float dd[8] = {c0.x, c0.y, c0.z, c0.w, c1.x, c1.y, c1.z, c1.w};
            #pragma unroll
            for (int k = 0; k < 8; ++k) {
                const float lf = left[k];
                const float m  = fminf(diag, fminf(up, lf));   // -> v_min3
                const float M  = fmaxf(diag, fmaxf(up, lf));   // -> v_max3
                const float md = __builtin_amdgcn_fmed3f(diag, up, lf);
                const float S  = 1.0f + __builtin_amdgcn_exp2f(m - md)
                                      + __builtin_amdgcn_exp2f(m - M);
                const float r  = dd[k] + m - __builtin_amdgcn_logf(S); // log2 HW op
                diag    = lf;
                left[k] = r;
                up      = r;
            }
            bottom = up;
        }
    }

    if (t == 63) out[b] = left[7] * LN2;       // R[N][N], unscaled
}

extern "C" void kernel_launch(void* const* d_in, const int* in_sizes, int n_in,
                              void* d_out, int out_size, void* d_ws, size_t ws_size,
                              hipStream_t stream) {
    const float* X = (const float*)d_in[0];
    const float* Y = (const float*)d_in[1];
    float* out = (float*)d_out;
    float* Dt  = (float*)d_ws;   // 64 MB scratch: transposed, log2e-scaled D

    cdist_kernel<<<dim3(4, 4, NB), 256, 0, stream>>>(X, Y, Dt);
    dtw_kernel<<<NB, 64, 0, stream>>>(Dt, out);
}

// Round 4
// 270.139 us; speedup vs baseline: 2.3320x; 1.1064x over previous
//
#include <hip/hip_runtime.h>
#include <math.h>

// Problem constants: B=64, N=512, d=64
#define NB 64
#define NN 512
#define ND 64

#define BIGV  1.0e10f                 // reference replaces inf with 1e10
#define LOG2E 1.4426950408889634f
#define LN2   0.6931471805599453f

typedef __attribute__((ext_vector_type(8))) short  bf16x8;  // 8 bf16 in 4 VGPRs
typedef __attribute__((ext_vector_type(4))) float  f32x4;

// fp32 -> bf16 bits, round-to-nearest-even (inputs are finite)
static __device__ __forceinline__ short f2bf(float f) {
    unsigned u = __float_as_uint(f);
    u += 0x7FFFu + ((u >> 16) & 1u);
    return (short)(u >> 16);
}

// ---------------------------------------------------------------------------
// Kernel 1 (MFMA): Dt[b][j][i] = ||X[b][i]-Y[b][j]||_2 * LOG2E
//   = sqrt(max(nx[i]+ny[j]-2*(x.y),0)) * LOG2E
// Block: 256 thr = 4 waves in 2x2; each wave computes a 64x64 tile of the
// 128x128 block tile. A-operand = Y rows (m=j), B-operand = X rows (n=i) so
// the C/D fast dim (lane&15) is i -> coalesced transposed store.
// MFMA 16x16x32 bf16 layouts (HW-verified per guide):
//   A[m][k]: lane = quad*16+m, elems k = quad*8+jj ;  B symmetric (n=lane&15)
//   C/D:     col(n) = lane&15, row(m) = quad*4+reg
// ---------------------------------------------------------------------------
__global__ __launch_bounds__(256) void cdist_kernel(const float* __restrict__ X,
                                                    const float* __restrict__ Y,
                                                    float* __restrict__ Dt) {
    __shared__ float nxs[128];   // |X row|^2 for this block's i-range
    __shared__ float nys[128];   // |Y row|^2 for this block's j-range

    const int b  = blockIdx.z;
    const int ib = blockIdx.x * 128;   // i base (X rows)
    const int jb = blockIdx.y * 128;   // j base (Y rows)
    const int t  = threadIdx.x;

    // --- block-cooperative row norms (one thread per row, fp32 exact) ---
    {
        const int r = t & 127;
        const float* src = (t < 128)
            ? (X + ((size_t)b * NN + ib + r) * ND)
            : (Y + ((size_t)b * NN + jb + r) * ND);
        float s = 0.f;
        #pragma unroll
        for (int k = 0; k < ND; k += 4) {
            float4 v = *(const float4*)(src + k);
            s += v.x * v.x + v.y * v.y + v.z * v.z + v.w * v.w;
        }
        if (t < 128) nxs[r] = s; else nys[r] = s;
    }
    __syncthreads();

    const int wave = t >> 6;
    const int wi   = (wave & 1) * 64;   // i offset of this wave's 64x64 tile
    const int wj   = (wave >> 1) * 64;  // j offset
    const int lane = t & 63;
    const int lm   = lane & 15;
    const int quad = lane >> 4;

    f32x4 acc[4][4];
    #pragma unroll
    for (int mt = 0; mt < 4; ++mt)
        #pragma unroll
        for (int nt = 0; nt < 4; ++nt)
            acc[mt][nt] = (f32x4){0.f, 0.f, 0.f, 0.f};

    #pragma unroll
    for (int h = 0; h < 2; ++h) {
        bf16x8 Af[4], Bf[4];
        #pragma unroll
        for (int mt = 0; mt < 4; ++mt) {         // A from Y rows (m = j dim)
            const float* p = Y + ((size_t)b * NN + jb + wj + mt * 16 + lm) * ND
                               + h * 32 + quad * 8;
            float4 v0 = *(const float4*)p;
            float4 v1 = *(const float4*)(p + 4);
            bf16x8 a;
            a[0] = f2bf(v0.x); a[1] = f2bf(v0.y); a[2] = f2bf(v0.z); a[3] = f2bf(v0.w);
            a[4] = f2bf(v1.x); a[5] = f2bf(v1.y); a[6] = f2bf(v1.z); a[7] = f2bf(v1.w);
            Af[mt] = a;
        }
        #pragma unroll
        for (int nt = 0; nt < 4; ++nt) {         // B from X rows (n = i dim)
            const float* p = X + ((size_t)b * NN + ib + wi + nt * 16 + lm) * ND
                               + h * 32 + quad * 8;
            float4 v0 = *(const float4*)p;
            float4 v1 = *(const float4*)(p + 4);
            bf16x8 a;
            a[0] = f2bf(v0.x); a[1] = f2bf(v0.y); a[2] = f2bf(v0.z); a[3] = f2bf(v0.w);
            a[4] = f2bf(v1.x); a[5] = f2bf(v1.y); a[6] = f2bf(v1.z); a[7] = f2bf(v1.w);
            Bf[nt] = a;
        }
        #pragma unroll
        for (int mt = 0; mt < 4; ++mt)
            #pragma unroll
            for (int nt = 0; nt < 4; ++nt)
                acc[mt][nt] = __builtin_amdgcn_mfma_f32_16x16x32_bf16(
                    Af[mt], Bf[nt], acc[mt][nt], 0, 0, 0);
    }

    // --- epilogue: d2 = ny[j] + nx[i] - 2*s; Dt[b][j][i] = sqrt(max(d2,0))*LOG2E
    float nxv[4], nyv[4][4];
    #pragma unroll
    for (int nt = 0; nt < 4; ++nt) nxv[nt] = nxs[wi + nt * 16 + lm];
    #pragma unroll
    for (int mt = 0; mt < 4; ++mt)
        #pragma unroll
        for (int r = 0; r < 4; ++r) nyv[mt][r] = nys[wj + mt * 16 + quad * 4 + r];

    #pragma unroll
    for (int mt = 0; mt < 4; ++mt) {
        const int j = jb + wj + mt * 16 + quad * 4;
        float* Drow = Dt + ((size_t)b * NN + j) * NN + ib + wi + lm;
        #pragma unroll
        for (int r = 0; r < 4; ++r) {
            #pragma unroll
            for (int nt = 0; nt < 4; ++nt) {
                float d2 = nyv[mt][r] + nxv[nt] - 2.0f * acc[mt][nt][r];
                Drow[(size_t)r * NN + nt * 16] = sqrtf(fmaxf(d2, 0.f)) * LOG2E;
            }
        }
    }
}

// ---------------------------------------------------------------------------
// Kernel 2: soft-DTW DP, one WAVE per batch, barrier-free.
// Lane t owns DP rows 8t+1..8t+8; lanes skewed by one column. Neighbor pass
// via DPP wave_shr:1 (lane i <- lane i-1; lane 0 <- old = BIGV).
// Prefetch: 4-slot register ring with compile-time slot index inside a 4x
// unrolled loop — NO register rotation, so the compiler can keep ~8 loads
// in flight and emit partial vmcnt waits (the R3 rotation forced an
// effective depth-1 pipeline => ~500 stall cyc/iter).
// Base-2 domain: r = d + m - log2(1 + 2^(m-med) + 2^(m-max)).
// ---------------------------------------------------------------------------
__global__ __launch_bounds__(64) void dtw_kernel(const float* __restrict__ Dt,
                                                 float* __restrict__ out) {
    const int b = blockIdx.x;
    const int t = threadIdx.x;                 // lane 0..63
    const float* __restrict__ Db = Dt + (size_t)b * NN * NN;
    const int ib = 8 * t;                      // first owned D-row

    float left[8];
    #pragma unroll
    for (int k = 0; k < 8; ++k) left[k] = BIGV;

    float topU   = (t == 0) ? 0.0f : BIGV;     // becomes diag R[0][0]=0 at ss=0
    float bottom = BIGV;

    // ring slot u holds this lane's D column consumed at iteration ss≡u (mod 4)
    float4 ra[4], rb[4];
    #pragma unroll
    for (int u = 0; u < 4; ++u) {
        const int col = u - t + 1;             // column consumed at ss=u
        if (col >= 1) {                        // col<=4<=NN always
            const float* p = Db + (size_t)(col - 1) * NN + ib;
            ra[u] = *(const float4*)(p);
            rb[u] = *(const float4*)(p + 4);
        }
    }

    for (int sb = 0; sb < 576; sb += 4) {      // ss = 0..575 (>= NN+63-1)
        #pragma unroll
        for (int u = 0; u < 4; ++u) {
            const int ss = sb + u;
            // lane t receives lane t-1's bottom (prev step); lane 0 gets BIGV
            const float recv = __int_as_float(__builtin_amdgcn_update_dpp(
                __float_as_int(BIGV), __float_as_int(bottom),
                0x138 /*wave_shr:1*/, 0xf, 0xf, false));
            const float topL = topU;           // R[ib][j-1]
            topU = recv;                       // R[ib][j]

            const int j = ss - t + 1;
            const float4 c0 = ra[u], c1 = rb[u];

            const int jn = j + 4;              // refill this slot 4 cols ahead
            if (jn >= 1 && jn <= NN) {
                const float* p = Db + (size_t)(jn - 1) * NN + ib;
                ra[u] = *(const float4*)(p);
                rb[u] = *(const float4*)(p + 4);
            }

            if (j >= 1 && j <= NN) {
                float up = topU, diag = topL;
                const float dd[8] = {c0.x, c0.y, c0.z, c0.w,
                                     c1.x, c1.y, c1.z, c1.w};
                #pragma unroll
                for (int k = 0; k < 8; ++k) {
                    const float lf = left[k];
                    const float m  = fminf(diag, fminf(up, lf));   // v_min3
                    const float M  = fmaxf(diag, fmaxf(up, lf));   // v_max3
                    const float md = __builtin_amdgcn_fmed3f(diag, up, lf);
                    const float S  = 1.0f + __builtin_amdgcn_exp2f(m - md)
                                          + __builtin_amdgcn_exp2f(m - M);
                    const float r  = dd[k] + m - __builtin_amdgcn_logf(S); // log2
                    diag    = lf;
                    left[k] = r;
                    up      = r;
                }
                bottom = up;
            }
        }
    }

    if (t == 63) out[b] = left[7] * LN2;       // R[N][N], unscaled
}

extern "C" void kernel_launch(void* const* d_in, const int* in_sizes, int n_in,
                              void* d_out, int out_size, void* d_ws, size_t ws_size,
                              hipStream_t stream) {
    const float* X = (const float*)d_in[0];
    const float* Y = (const float*)d_in[1];
    float* out = (float*)d_out;
    float* Dt  = (float*)d_ws;   // 64 MB scratch: transposed, log2e-scaled D

    cdist_kernel<<<dim3(4, 4, NB), 256, 0, stream>>>(X, Y, Dt);
    dtw_kernel<<<NB, 64, 0, stream>>>(Dt, out);
}

// Round 8
// 255.773 us; speedup vs baseline: 2.4630x; 1.0562x over previous
//
#include <hip/hip_runtime.h>
#include <math.h>

// Problem constants: B=64, N=512, d=64
#define NB 64
#define NN 512
#define ND 64

#define BIGV  1.0e10f                 // reference replaces inf with 1e10
#define LOG2E 1.4426950408889634f
#define LN2   0.6931471805599453f
#define RING  12                      // prefetch ring depth (columns in flight)

typedef __attribute__((ext_vector_type(8))) short  bf16x8;  // 8 bf16 in 4 VGPRs
typedef __attribute__((ext_vector_type(4))) float  f32x4;

// fp32 -> bf16 bits, round-to-nearest-even (inputs are finite)
static __device__ __forceinline__ short f2bf(float f) {
    unsigned u = __float_as_uint(f);
    u += 0x7FFFu + ((u >> 16) & 1u);
    return (short)(u >> 16);
}

// ---------------------------------------------------------------------------
// Kernel 1 (MFMA): Dt[b][j][i] = ||X[b][i]-Y[b][j]||_2 * LOG2E
//   = sqrt(max(nx[i]+ny[j]-2*(x.y),0)) * LOG2E   (base-2-domain scaled)
// Block: 256 thr = 4 waves in 2x2; each wave a 64x64 tile of the 128x128
// block tile. A-operand = Y rows (m=j), B-operand = X rows (n=i) so the C/D
// fast dim (lane&15) is i -> coalesced transposed store.
// (unchanged from R4 — passed with absmax 0.0)
// ---------------------------------------------------------------------------
__global__ __launch_bounds__(256) void cdist_kernel(const float* __restrict__ X,
                                                    const float* __restrict__ Y,
                                                    float* __restrict__ Dt) {
    __shared__ float nxs[128];   // |X row|^2 for this block's i-range
    __shared__ float nys[128];   // |Y row|^2 for this block's j-range

    const int b  = blockIdx.z;
    const int ib = blockIdx.x * 128;   // i base (X rows)
    const int jb = blockIdx.y * 128;   // j base (Y rows)
    const int t  = threadIdx.x;

    // --- block-cooperative row norms (one thread per row, fp32 exact) ---
    {
        const int r = t & 127;
        const float* src = (t < 128)
            ? (X + ((size_t)b * NN + ib + r) * ND)
            : (Y + ((size_t)b * NN + jb + r) * ND);
        float s = 0.f;
        #pragma unroll
        for (int k = 0; k < ND; k += 4) {
            float4 v = *(const float4*)(src + k);
            s += v.x * v.x + v.y * v.y + v.z * v.z + v.w * v.w;
        }
        if (t < 128) nxs[r] = s; else nys[r] = s;
    }
    __syncthreads();

    const int wave = t >> 6;
    const int wi   = (wave & 1) * 64;   // i offset of this wave's 64x64 tile
    const int wj   = (wave >> 1) * 64;  // j offset
    const int lane = t & 63;
    const int lm   = lane & 15;
    const int quad = lane >> 4;

    f32x4 acc[4][4];
    #pragma unroll
    for (int mt = 0; mt < 4; ++mt)
        #pragma unroll
        for (int nt = 0; nt < 4; ++nt)
            acc[mt][nt] = (f32x4){0.f, 0.f, 0.f, 0.f};

    #pragma unroll
    for (int h = 0; h < 2; ++h) {
        bf16x8 Af[4], Bf[4];
        #pragma unroll
        for (int mt = 0; mt < 4; ++mt) {         // A from Y rows (m = j dim)
            const float* p = Y + ((size_t)b * NN + jb + wj + mt * 16 + lm) * ND
                               + h * 32 + quad * 8;
            float4 v0 = *(const float4*)p;
            float4 v1 = *(const float4*)(p + 4);
            bf16x8 a;
            a[0] = f2bf(v0.x); a[1] = f2bf(v0.y); a[2] = f2bf(v0.z); a[3] = f2bf(v0.w);
            a[4] = f2bf(v1.x); a[5] = f2bf(v1.y); a[6] = f2bf(v1.z); a[7] = f2bf(v1.w);
            Af[mt] = a;
        }
        #pragma unroll
        for (int nt = 0; nt < 4; ++nt) {         // B from X rows (n = i dim)
            const float* p = X + ((size_t)b * NN + ib + wi + nt * 16 + lm) * ND
                               + h * 32 + quad * 8;
            float4 v0 = *(const float4*)p;
            float4 v1 = *(const float4*)(p + 4);
            bf16x8 a;
            a[0] = f2bf(v0.x); a[1] = f2bf(v0.y); a[2] = f2bf(v0.z); a[3] = f2bf(v0.w);
            a[4] = f2bf(v1.x); a[5] = f2bf(v1.y); a[6] = f2bf(v1.z); a[7] = f2bf(v1.w);
            Bf[nt] = a;
        }
        #pragma unroll
        for (int mt = 0; mt < 4; ++mt)
            #pragma unroll
            for (int nt = 0; nt < 4; ++nt)
                acc[mt][nt] = __builtin_amdgcn_mfma_f32_16x16x32_bf16(
                    Af[mt], Bf[nt], acc[mt][nt], 0, 0, 0);
    }

    // --- epilogue: d2 = ny[j]+nx[i]-2*s; Dt = sqrt(max(d2,0)) * LOG2E
    float nxv[4], nyv[4][4];
    #pragma unroll
    for (int nt = 0; nt < 4; ++nt) nxv[nt] = nxs[wi + nt * 16 + lm];
    #pragma unroll
    for (int mt = 0; mt < 4; ++mt)
        #pragma unroll
        for (int r = 0; r < 4; ++r) nyv[mt][r] = nys[wj + mt * 16 + quad * 4 + r];

    #pragma unroll
    for (int mt = 0; mt < 4; ++mt) {
        const int j = jb + wj + mt * 16 + quad * 4;
        float* Drow = Dt + ((size_t)b * NN + j) * NN + ib + wi + lm;
        #pragma unroll
        for (int r = 0; r < 4; ++r) {
            #pragma unroll
            for (int nt = 0; nt < 4; ++nt) {
                float d2 = nyv[mt][r] + nxv[nt] - 2.0f * acc[mt][nt][r];
                Drow[(size_t)r * NN + nt * 16] = sqrtf(fmaxf(d2, 0.f)) * LOG2E;
            }
        }
    }
}

// ---------------------------------------------------------------------------
// Kernel 2: soft-DTW DP (LOG domain — R4's twice-proven math), one wave per
// batch, barrier-free. Lane t owns rows 8t+1..8t+8; lanes skewed by one
// column; neighbor pass via DPP wave_shr:1 (lane0 gets old=BIGV for free).
// Base-2 domain: r = d + m - log2(1 + 2^(m-med) + 2^(m-max)).
// CHANGE vs R4: prefetch ring loads are UNCONDITIONAL with clamped column
// index (clamped values are dead — consumption is guarded by the same
// j-range test). Removes the divergent-branch control dependence that
// forced conservative vmcnt drains (~400 stall cyc/step in R4); 12 slots
// refilled 12 columns ahead fully cover L3/HBM latency.
// ---------------------------------------------------------------------------
__global__ __launch_bounds__(64) void dtw_kernel(const float* __restrict__ Dt,
                                                 float* __restrict__ out) {
    const int b = blockIdx.x;
    const int t = threadIdx.x;                 // lane 0..63
    const float* __restrict__ Db = Dt + (size_t)b * NN * NN;
    const int ib = 8 * t;                      // first owned D-row

    float left[8];
    #pragma unroll
    for (int k = 0; k < 8; ++k) left[k] = BIGV;

    float topU   = (t == 0) ? 0.0f : BIGV;     // becomes diag R[0][0]=0 at ss=0
    float bottom = BIGV;

    // ring slot u holds this lane's D column consumed at step ss≡u (mod RING)
    float4 ra[RING], rb[RING];
    #pragma unroll
    for (int u = 0; u < RING; ++u) {
        int col = u - t + 1;
        col = col < 1 ? 1 : col;               // clamp; dead if OOB (u<RING<=NN)
        const float* p = Db + (size_t)(col - 1) * NN + ib;
        ra[u] = *(const float4*)(p);
        rb[u] = *(const float4*)(p + 4);
    }

    for (int sb = 0; sb < 576; sb += RING) {   // ss = 0..575 (= NN+63)
        #pragma unroll
        for (int u = 0; u < RING; ++u) {
            const int ss = sb + u;
            // lane t receives lane t-1's bottom (prev step); lane 0 gets BIGV
            const float recv = __int_as_float(__builtin_amdgcn_update_dpp(
                __float_as_int(BIGV), __float_as_int(bottom),
                0x138 /*wave_shr:1*/, 0xf, 0xf, false));
            const float topL = topU;           // R[ib][j-1]
            topU = recv;                       // R[ib][j]

            const int j = ss - t + 1;
            const float4 c0 = ra[u], c1 = rb[u];

            // refill slot u for step ss+RING — UNCONDITIONAL, clamped
            {
                int jn = j + RING;
                jn = jn < 1 ? 1 : (jn > NN ? NN : jn);
                const float* p = Db + (size_t)(jn - 1) * NN + ib;
                ra[u] = *(const float4*)(p);
                rb[u] = *(const float4*)(p + 4);
            }

            if (j >= 1 && j <= NN) {
                float up = topU, diag = topL;
                const float dd[8] = {c0.x, c0.y, c0.z, c0.w,
                                     c1.x, c1.y, c1.z, c1.w};
                #pragma unroll
                for (int k = 0; k < 8; ++k) {
                    const float lf = left[k];
                    const float m  = fminf(diag, fminf(up, lf));   // v_min3
                    const float M  = fmaxf(diag, fmaxf(up, lf));   // v_max3
                    const float md = __builtin_amdgcn_fmed3f(diag, up, lf);
                    const float S  = 1.0f + __builtin_amdgcn_exp2f(m - md)
                                          + __builtin_amdgcn_exp2f(m - M);
                    const float r  = dd[k] + m - __builtin_amdgcn_logf(S); // log2
                    diag    = lf;
                    left[k] = r;
                    up      = r;
                }
                bottom = up;
            }
        }
    }

    if (t == 63) out[b] = left[7] * LN2;       // R[N][N], unscaled
}

extern "C" void kernel_launch(void* const* d_in, const int* in_sizes, int n_in,
                              void* d_out, int out_size, void* d_ws, size_t ws_size,
                              hipStream_t stream) {
    const float* X = (const float*)d_in[0];
    const float* Y = (const float*)d_in[1];
    float* out = (float*)d_out;
    float* Dt  = (float*)d_ws;   // 64 MB scratch: transposed, log2e-scaled D

    cdist_kernel<<<dim3(4, 4, NB), 256, 0, stream>>>(X, Y, Dt);
    dtw_kernel<<<NB, 64, 0, stream>>>(Dt, out);
}

// Round 9
// 192.696 us; speedup vs baseline: 3.2693x; 1.3273x over previous
//
#include <hip/hip_runtime.h>
#include <math.h>

// Problem constants: B=64, N=512, d=64
#define NB 64
#define NN 512
#define ND 64

#define LOG2E 1.4426950408889634f
#define LN2   0.6931471805599453f
#define RING  12                      // prefetch ring depth (columns in flight)
#define NINF  __int_as_float(0xFF800000u)   // -inf

typedef __attribute__((ext_vector_type(8))) short  bf16x8;  // 8 bf16 in 4 VGPRs
typedef __attribute__((ext_vector_type(4))) float  f32x4;

// fp32 -> bf16 bits, round-to-nearest-even (inputs are finite)
static __device__ __forceinline__ short f2bf(float f) {
    unsigned u = __float_as_uint(f);
    u += 0x7FFFu + ((u >> 16) & 1u);
    return (short)(u >> 16);
}

// ---------------------------------------------------------------------------
// Kernel 1 (MFMA): Wt[b][j][i] = exp2(16 - log2(e)*||X[b][i]-Y[b][j]||)
// = 2^16 * e^{-dist}: the anti-diagonal-scaled exp-domain weight.
// Body identical to the R4/R8-proven kernel; only the epilogue store differs.
// ---------------------------------------------------------------------------
__global__ __launch_bounds__(256) void cdist_kernel(const float* __restrict__ X,
                                                    const float* __restrict__ Y,
                                                    float* __restrict__ Wt) {
    __shared__ float nxs[128];   // |X row|^2 for this block's i-range
    __shared__ float nys[128];   // |Y row|^2 for this block's j-range

    const int b  = blockIdx.z;
    const int ib = blockIdx.x * 128;   // i base (X rows)
    const int jb = blockIdx.y * 128;   // j base (Y rows)
    const int t  = threadIdx.x;

    // --- block-cooperative row norms (one thread per row, fp32 exact) ---
    {
        const int r = t & 127;
        const float* src = (t < 128)
            ? (X + ((size_t)b * NN + ib + r) * ND)
            : (Y + ((size_t)b * NN + jb + r) * ND);
        float s = 0.f;
        #pragma unroll
        for (int k = 0; k < ND; k += 4) {
            float4 v = *(const float4*)(src + k);
            s += v.x * v.x + v.y * v.y + v.z * v.z + v.w * v.w;
        }
        if (t < 128) nxs[r] = s; else nys[r] = s;
    }
    __syncthreads();

    const int wave = t >> 6;
    const int wi   = (wave & 1) * 64;   // i offset of this wave's 64x64 tile
    const int wj   = (wave >> 1) * 64;  // j offset
    const int lane = t & 63;
    const int lm   = lane & 15;
    const int quad = lane >> 4;

    f32x4 acc[4][4];
    #pragma unroll
    for (int mt = 0; mt < 4; ++mt)
        #pragma unroll
        for (int nt = 0; nt < 4; ++nt)
            acc[mt][nt] = (f32x4){0.f, 0.f, 0.f, 0.f};

    #pragma unroll
    for (int h = 0; h < 2; ++h) {
        bf16x8 Af[4], Bf[4];
        #pragma unroll
        for (int mt = 0; mt < 4; ++mt) {         // A from Y rows (m = j dim)
            const float* p = Y + ((size_t)b * NN + jb + wj + mt * 16 + lm) * ND
                               + h * 32 + quad * 8;
            float4 v0 = *(const float4*)p;
            float4 v1 = *(const float4*)(p + 4);
            bf16x8 a;
            a[0] = f2bf(v0.x); a[1] = f2bf(v0.y); a[2] = f2bf(v0.z); a[3] = f2bf(v0.w);
            a[4] = f2bf(v1.x); a[5] = f2bf(v1.y); a[6] = f2bf(v1.z); a[7] = f2bf(v1.w);
            Af[mt] = a;
        }
        #pragma unroll
        for (int nt = 0; nt < 4; ++nt) {         // B from X rows (n = i dim)
            const float* p = X + ((size_t)b * NN + ib + wi + nt * 16 + lm) * ND
                               + h * 32 + quad * 8;
            float4 v0 = *(const float4*)p;
            float4 v1 = *(const float4*)(p + 4);
            bf16x8 a;
            a[0] = f2bf(v0.x); a[1] = f2bf(v0.y); a[2] = f2bf(v0.z); a[3] = f2bf(v0.w);
            a[4] = f2bf(v1.x); a[5] = f2bf(v1.y); a[6] = f2bf(v1.z); a[7] = f2bf(v1.w);
            Bf[nt] = a;
        }
        #pragma unroll
        for (int mt = 0; mt < 4; ++mt)
            #pragma unroll
            for (int nt = 0; nt < 4; ++nt)
                acc[mt][nt] = __builtin_amdgcn_mfma_f32_16x16x32_bf16(
                    Af[mt], Bf[nt], acc[mt][nt], 0, 0, 0);
    }

    // --- epilogue: d2 = ny[j]+nx[i]-2*s; W = exp2(16 - LOG2E*sqrt(max(d2,0)))
    float nxv[4], nyv[4][4];
    #pragma unroll
    for (int nt = 0; nt < 4; ++nt) nxv[nt] = nxs[wi + nt * 16 + lm];
    #pragma unroll
    for (int mt = 0; mt < 4; ++mt)
        #pragma unroll
        for (int r = 0; r < 4; ++r) nyv[mt][r] = nys[wj + mt * 16 + quad * 4 + r];

    #pragma unroll
    for (int mt = 0; mt < 4; ++mt) {
        const int j = jb + wj + mt * 16 + quad * 4;
        float* Drow = Wt + ((size_t)b * NN + j) * NN + ib + wi + lm;
        #pragma unroll
        for (int r = 0; r < 4; ++r) {
            #pragma unroll
            for (int nt = 0; nt < 4; ++nt) {
                float d2 = nyv[mt][r] + nxv[nt] - 2.0f * acc[mt][nt][r];
                float w  = __builtin_amdgcn_exp2f(16.0f - LOG2E * sqrtf(fmaxf(d2, 0.f)));
                Drow[(size_t)r * NN + nt * 16] = w;
            }
        }
    }
}

// ---------------------------------------------------------------------------
// Kernel 2: soft-DTW DP, exp-domain chain with ABSOLUTE LOG-DOMAIN handoff.
//   F[i][j] = 2^(16(i+j)) e^{-R[i][j]};  F = W*(2^16 F_diag + F_up + F_left)
// Lane state: L[k] = F(row ib+1+k, col j) * 2^Ot  (stored domain), Ot float.
// Handoff: h = log2(L[7]) - Ot = log2(F) — ABSOLUTE, scale-free. Receiver:
// up0 = exp2(h + Ot_self); the h+Ot near-cancellation is fp32-EXACT
// (same-magnitude subtraction), so no cross-lane scale sync exists at all
// (the R5-R7 failure mechanism is structurally removed).
// Activation (ss==t): adopt Ot = -h_recv => up0 = 1 by construction.
// Pre-activation h = -inf => exp2 gives exact 0 boundaries (incl. lane 0 via
// DPP old = -inf); lane 0's R[0][0]=0 diag seeded via diagHold = 2^16.
// Renorm: band max(L) in [2^-20,2^20], *2^±40, Ot += ±40 (rare: drift is
// 16 - d*log2e ~ -0.3 bit/col). Safety: exp2 arg clamped to <=60 -> worst
// intermediate 2^93, finite. Chain per cell: ONE fma.
// Ring loads: unconditional clamped (R8-proven).
// ---------------------------------------------------------------------------
__global__ __launch_bounds__(64) void dtw_kernel(const float* __restrict__ Wt,
                                                 float* __restrict__ out) {
    const int b = blockIdx.x;
    const int t = threadIdx.x;                 // lane 0..63
    const float* __restrict__ Wb = Wt + (size_t)b * NN * NN;
    const int ib = 8 * t;                      // first owned row of W column

    float L[8];
    #pragma unroll
    for (int k = 0; k < 8; ++k) L[k] = 0.0f;   // F(inf) = 0 boundary

    float diagHold = (t == 0) ? 65536.0f : 0.0f;  // 2^16 * F[0][0] for lane 0
    float h        = NINF;                     // my bottom row, log2(F) domain
    float Otf      = 0.0f;                     // stored = F * 2^Ot

    // prefetch ring: slot u holds the 8 W values of the column consumed at
    // step ss == u (mod RING). Unconditional clamped loads (R8-proven).
    float4 ra[RING], rb[RING];
    #pragma unroll
    for (int u = 0; u < RING; ++u) {
        int col = u - t + 1;
        col = col < 1 ? 1 : col;               // clamp; dead if OOB
        const float* p = Wb + (size_t)(col - 1) * NN + ib;
        ra[u] = *(const float4*)(p);
        rb[u] = *(const float4*)(p + 4);
    }

    for (int sb = 0; sb < 576; sb += RING) {   // ss = 0..575
        #pragma unroll
        for (int u = 0; u < RING; ++u) {
            const int ss = sb + u;
            // lane t receives lane t-1's h (prev step); lane 0 gets -inf
            const float recvH = __int_as_float(__builtin_amdgcn_update_dpp(
                (int)0xFF800000, __float_as_int(h),
                0x138 /*wave_shr:1*/, 0xf, 0xf, false));

            // activation: adopt neighbor's scale => up0 = 2^0 = 1, exact.
            if (ss == t && t > 0) Otf = -recvH;

            const float up0 = __builtin_amdgcn_exp2f(fminf(recvH + Otf, 60.0f));
            const float diag0 = diagHold;      // 2^16 * F[ib][j-1], stored dom.
            diagHold = up0 * 65536.0f;         // 2^16 * F[ib][j] for next step

            const int j = ss - t + 1;
            const float4 c0 = ra[u], c1 = rb[u];

            // refill slot u for step ss+RING — unconditional, clamped
            {
                int jn = j + RING;
                jn = jn < 1 ? 1 : (jn > NN ? NN : jn);
                const float* p = Wb + (size_t)(jn - 1) * NN + ib;
                ra[u] = *(const float4*)(p);
                rb[u] = *(const float4*)(p + 4);
            }

            if (j >= 1 && j <= NN) {
                const float dd[8] = {c0.x, c0.y, c0.z, c0.w,
                                     c1.x, c1.y, c1.z, c1.w};
                float pre[8], cc[8];
                pre[0] = diag0 + L[0];         // diag0 already carries 2^16
                #pragma unroll
                for (int k = 1; k < 8; ++k)    // 2^16*diag + left (off-chain)
                    pre[k] = fmaf(65536.0f, L[k - 1], L[k]);
                #pragma unroll
                for (int k = 0; k < 8; ++k) cc[k] = dd[k] * pre[k];
                float r = up0;
                #pragma unroll
                for (int k = 0; k < 8; ++k) {  // the only serial chain: 8 fma
                    r = fmaf(dd[k], r, cc[k]);
                    L[k] = r;
                }

                // renorm: keep max(L) inside [2^-20, 2^20] (rare)
                float m8 = fmaxf(fmaxf(fmaxf(L[0], L[1]), fmaxf(L[2], L[3])),
                                 fmaxf(fmaxf(L[4], L[5]), fmaxf(L[6], L[7])));
                if (m8 > 0x1p20f || (m8 < 0x1p-20f && m8 > 0.0f)) {
                    const bool  big = (m8 > 0x1p20f);
                    const float sc  = big ? 0x1p-40f : 0x1p40f;
                    #pragma unroll
                    for (int k = 0; k < 8; ++k) L[k] *= sc;
                    diagHold *= sc;
                    Otf += big ? -40.0f : 40.0f;
                }

                // absolute log-domain handoff (invariant under renorm)
                h = __builtin_amdgcn_logf(L[7]) - Otf;   // v_log_f32 = log2
            }
        }
    }

    // R[N][N] = (16*1024 - log2 F) * ln2,  log2 F = h (lane 63's last bottom)
    if (t == 63) out[b] = (16384.0f - h) * LN2;
}

extern "C" void kernel_launch(void* const* d_in, const int* in_sizes, int n_in,
                              void* d_out, int out_size, void* d_ws, size_t ws_size,
                              hipStream_t stream) {
    const float* X = (const float*)d_in[0];
    const float* Y = (const float*)d_in[1];
    float* out = (float*)d_out;
    float* Wt  = (float*)d_ws;   // 64 MB scratch: transposed W = 2^16 e^{-dist}

    cdist_kernel<<<dim3(4, 4, NB), 256, 0, stream>>>(X, Y, Wt);
    dtw_kernel<<<NB, 64, 0, stream>>>(Wt, out);
}

// Round 11
// 165.140 us; speedup vs baseline: 3.8148x; 1.1669x over previous
//
#include <hip/hip_runtime.h>
#include <math.h>

// Problem constants: B=64, N=512, d=64
#define NB 64
#define NN 512
#define ND 64

#define LOG2E 1.4426950408889634f
#define LN2   0.6931471805599453f
#define RING  12                      // prefetch ring depth (columns in flight)
#define NINF  __int_as_float(0xFF800000u)   // -inf

typedef __attribute__((ext_vector_type(8))) short  bf16x8;  // 8 bf16 in 4 VGPRs
typedef __attribute__((ext_vector_type(4))) float  f32x4;

// fp32 -> bf16 bits, round-to-nearest-even (inputs are finite)
static __device__ __forceinline__ unsigned short f2bf(float f) {
    unsigned u = __float_as_uint(f);
    u += 0x7FFFu + ((u >> 16) & 1u);
    return (unsigned short)(u >> 16);
}

// ---------------------------------------------------------------------------
// Kernel 1 (MFMA): Wt[b][j][i] = bf16( exp2(16 - log2e*||X[b][i]-Y[b][j]||) )
// = 2^16 * e^{-dist}: anti-diagonal-scaled exp-domain weight, stored bf16
// (W in [2^-9, 2^16], never denormal in bf16). R10-proven body.
// ---------------------------------------------------------------------------
__global__ __launch_bounds__(256) void cdist_kernel(const float* __restrict__ X,
                                                    const float* __restrict__ Y,
                                                    unsigned short* __restrict__ Wt) {
    __shared__ float nxs[128];   // |X row|^2 for this block's i-range
    __shared__ float nys[128];   // |Y row|^2 for this block's j-range

    const int b  = blockIdx.z;
    const int ib = blockIdx.x * 128;   // i base (X rows)
    const int jb = blockIdx.y * 128;   // j base (Y rows)
    const int t  = threadIdx.x;

    // --- block-cooperative row norms (one thread per row, fp32 exact) ---
    {
        const int r = t & 127;
        const float* src = (t < 128)
            ? (X + ((size_t)b * NN + ib + r) * ND)
            : (Y + ((size_t)b * NN + jb + r) * ND);
        float s = 0.f;
        #pragma unroll
        for (int k = 0; k < ND; k += 4) {
            float4 v = *(const float4*)(src + k);
            s += v.x * v.x + v.y * v.y + v.z * v.z + v.w * v.w;
        }
        if (t < 128) nxs[r] = s; else nys[r] = s;
    }
    __syncthreads();

    const int wave = t >> 6;
    const int wi   = (wave & 1) * 64;   // i offset of this wave's 64x64 tile
    const int wj   = (wave >> 1) * 64;  // j offset
    const int lane = t & 63;
    const int lm   = lane & 15;
    const int quad = lane >> 4;

    f32x4 acc[4][4];
    #pragma unroll
    for (int mt = 0; mt < 4; ++mt)
        #pragma unroll
        for (int nt = 0; nt < 4; ++nt)
            acc[mt][nt] = (f32x4){0.f, 0.f, 0.f, 0.f};

    #pragma unroll
    for (int h = 0; h < 2; ++h) {
        bf16x8 Af[4], Bf[4];
        #pragma unroll
        for (int mt = 0; mt < 4; ++mt) {         // A from Y rows (m = j dim)
            const float* p = Y + ((size_t)b * NN + jb + wj + mt * 16 + lm) * ND
                               + h * 32 + quad * 8;
            float4 v0 = *(const float4*)p;
            float4 v1 = *(const float4*)(p + 4);
            bf16x8 a;
            a[0] = f2bf(v0.x); a[1] = f2bf(v0.y); a[2] = f2bf(v0.z); a[3] = f2bf(v0.w);
            a[4] = f2bf(v1.x); a[5] = f2bf(v1.y); a[6] = f2bf(v1.z); a[7] = f2bf(v1.w);
            Af[mt] = a;
        }
        #pragma unroll
        for (int nt = 0; nt < 4; ++nt) {         // B from X rows (n = i dim)
            const float* p = X + ((size_t)b * NN + ib + wi + nt * 16 + lm) * ND
                               + h * 32 + quad * 8;
            float4 v0 = *(const float4*)p;
            float4 v1 = *(const float4*)(p + 4);
            bf16x8 a;
            a[0] = f2bf(v0.x); a[1] = f2bf(v0.y); a[2] = f2bf(v0.z); a[3] = f2bf(v0.w);
            a[4] = f2bf(v1.x); a[5] = f2bf(v1.y); a[6] = f2bf(v1.z); a[7] = f2bf(v1.w);
            Bf[nt] = a;
        }
        #pragma unroll
        for (int mt = 0; mt < 4; ++mt)
            #pragma unroll
            for (int nt = 0; nt < 4; ++nt)
                acc[mt][nt] = __builtin_amdgcn_mfma_f32_16x16x32_bf16(
                    Af[mt], Bf[nt], acc[mt][nt], 0, 0, 0);
    }

    // --- epilogue: d2 = ny[j]+nx[i]-2*s; W = exp2(16 - LOG2E*sqrt(max(d2,0)))
    float nxv[4], nyv[4][4];
    #pragma unroll
    for (int nt = 0; nt < 4; ++nt) nxv[nt] = nxs[wi + nt * 16 + lm];
    #pragma unroll
    for (int mt = 0; mt < 4; ++mt)
        #pragma unroll
        for (int r = 0; r < 4; ++r) nyv[mt][r] = nys[wj + mt * 16 + quad * 4 + r];

    #pragma unroll
    for (int mt = 0; mt < 4; ++mt) {
        const int j = jb + wj + mt * 16 + quad * 4;
        unsigned short* Drow = Wt + ((size_t)b * NN + j) * NN + ib + wi + lm;
        #pragma unroll
        for (int r = 0; r < 4; ++r) {
            #pragma unroll
            for (int nt = 0; nt < 4; ++nt) {
                float d2 = nyv[mt][r] + nxv[nt] - 2.0f * acc[mt][nt][r];
                float w  = __builtin_amdgcn_exp2f(16.0f - LOG2E * sqrtf(fmaxf(d2, 0.f)));
                Drow[(size_t)r * NN + nt * 16] = f2bf(w);
            }
        }
    }
}

// ---------------------------------------------------------------------------
// Kernel 2: soft-DTW DP, exp-domain chain, branchless steady phase.
// F[i][j] = 2^(16(i+j)) e^{-R}; F = W*(2^16 F_diag + F_up + F_left); ONE fma
// per cell on the serial chain. Handoff h = log2(L[7]) - Ot (absolute,
// scale-free — R9-proven).
// R10 POST-MORTEM: off-ridge drift is ±16 bits/STEP (column step doesn't
// extend the optimal path when i>>j), not ±0.3 — fixed ±40 renorm every 4
// steps diverges -> inf. FIX: branchless FULL normalization (exponent
// extraction, rescale max(L) to [1,2)) every 2nd step — handles any drift
// <= ~60 bits/period with uniform cost and no divergent branch.
// ---------------------------------------------------------------------------
static __device__ __forceinline__ void dtw_step(
    bool DOACT, bool DOGUARD, bool DOREN, bool DOCLAMP,
    int ss, int u, int t, const unsigned short* __restrict__ Wb, int ib,
    uint4* ring, float* L, float& diagHold, float& h, float& Otf)
{
    // lane t receives lane t-1's h (prev step); lane 0 gets -inf
    const float recvH = __int_as_float(__builtin_amdgcn_update_dpp(
        (int)0xFF800000, __float_as_int(h), 0x138 /*wave_shr:1*/, 0xf, 0xf, false));

    // activation: adopt neighbor's scale => up0 = 2^0 = 1, exact (R9-proven)
    if (DOACT) { if (ss == t && t > 0) Otf = -recvH; }

    const float up0   = __builtin_amdgcn_exp2f(fminf(recvH + Otf, 80.0f));
    const float diag0 = diagHold;              // 2^16 * F[ib][j-1], stored dom.
    diagHold = up0 * 65536.0f;                 // 2^16 * F[ib][j] for next step

    const int j = ss - t + 1;
    const uint4 c = ring[u];

    // refill slot u for step ss+RING (unconditional; overrun reads are dead)
    {
        int jn = j + RING;
        if (DOCLAMP) jn = jn < 1 ? 1 : jn;     // lower clamp (phase A only)
        ring[u] = *(const uint4*)(Wb + (size_t)(jn - 1) * NN + ib);
    }

    bool act = true;
    if (DOGUARD) act = (j >= 1) && (j <= NN);
    if (act) {
        float dd[8];                           // bf16 -> f32: shl/and, exact
        dd[0] = __uint_as_float(c.x << 16);
        dd[1] = __uint_as_float(c.x & 0xFFFF0000u);
        dd[2] = __uint_as_float(c.y << 16);
        dd[3] = __uint_as_float(c.y & 0xFFFF0000u);
        dd[4] = __uint_as_float(c.z << 16);
        dd[5] = __uint_as_float(c.z & 0xFFFF0000u);
        dd[6] = __uint_as_float(c.w << 16);
        dd[7] = __uint_as_float(c.w & 0xFFFF0000u);

        float pre[8], cc[8];
        pre[0] = diag0 + L[0];                 // diag0 already carries 2^16
        #pragma unroll
        for (int k = 1; k < 8; ++k)            // 2^16*diag + left (off-chain)
            pre[k] = fmaf(65536.0f, L[k - 1], L[k]);
        #pragma unroll
        for (int k = 0; k < 8; ++k) cc[k] = dd[k] * pre[k];
        float r = up0;
        #pragma unroll
        for (int k = 0; k < 8; ++k) {          // the only serial chain: 8 fma
            r = fmaf(dd[k], r, cc[k]);
            L[k] = r;
        }

        if (DOREN) {   // branchless FULL normalization: max(L) -> [1,2)
            float m8 = fmaxf(fmaxf(fmaxf(L[0], L[1]), fmaxf(L[2], L[3])),
                             fmaxf(fmaxf(L[4], L[5]), fmaxf(L[6], L[7])));
            const int   e  = (int)(__float_as_uint(m8) >> 23) - 127;
            const float sc = __uint_as_float((unsigned)(127 - e) << 23); // 2^-e
            #pragma unroll
            for (int k = 0; k < 8; ++k) L[k] *= sc;
            diagHold *= sc;
            Otf -= (float)e;                   // stored = F * 2^Ot invariant
        }

        // absolute log-domain handoff (invariant under renorm)
        h = __builtin_amdgcn_logf(L[7]) - Otf; // v_log_f32 = log2
    }
}

__global__ __launch_bounds__(64) void dtw_kernel(const unsigned short* __restrict__ Wt,
                                                 float* __restrict__ out) {
    const int b = blockIdx.x;
    const int t = threadIdx.x;                 // lane 0..63
    const unsigned short* __restrict__ Wb = Wt + (size_t)b * NN * NN;
    const int ib = 8 * t;                      // first owned row of W column

    float L[8];
    #pragma unroll
    for (int k = 0; k < 8; ++k) L[k] = 0.0f;   // F(inf) = 0 boundary

    float diagHold = (t == 0) ? 65536.0f : 0.0f;  // 2^16 * F[0][0] for lane 0
    float h        = NINF;                     // my bottom row, log2(F) domain
    float Otf      = 0.0f;                     // stored = F * 2^Ot

    // prefetch ring: slot u holds the 8 bf16 W values (one dwordx4) of the
    // column consumed at step ss == u (mod RING).
    uint4 ring[RING];
    #pragma unroll
    for (int u = 0; u < RING; ++u) {
        int col = u - t + 1;
        col = col < 1 ? 1 : col;               // clamp; dead if OOB
        ring[u] = *(const uint4*)(Wb + (size_t)(col - 1) * NN + ib);
    }

    // Phase A: guards + activation + lower clamp (ss 0..71)
    for (int sb = 0; sb < 72; sb += RING)
        #pragma unroll
        for (int u = 0; u < RING; ++u)
            dtw_step(true, true, (u & 1) == 1, true,
                     sb + u, u, t, Wb, ib, ring, L, diagHold, h, Otf);

    // Phase B: branchless hot loop (ss 72..503; all 64 lanes active)
    for (int sb = 72; sb < 504; sb += RING)
        #pragma unroll
        for (int u = 0; u < RING; ++u)
            dtw_step(false, false, (u & 1) == 1, false,
                     sb + u, u, t, Wb, ib, ring, L, diagHold, h, Otf);

    // Phase C: drain with j<=NN guard (ss 504..575)
    for (int sb = 504; sb < 576; sb += RING)
        #pragma unroll
        for (int u = 0; u < RING; ++u)
            dtw_step(false, true, (u & 1) == 1, false,
                     sb + u, u, t, Wb, ib, ring, L, diagHold, h, Otf);

    // R[N][N] = (16*1024 - log2 F) * ln2,  log2 F = h (lane 63, ss=574)
    if (t == 63) out[b] = (16384.0f - h) * LN2;
}

extern "C" void kernel_launch(void* const* d_in, const int* in_sizes, int n_in,
                              void* d_out, int out_size, void* d_ws, size_t ws_size,
                              hipStream_t stream) {
    const float* X = (const float*)d_in[0];
    const float* Y = (const float*)d_in[1];
    float* out = (float*)d_out;
    unsigned short* Wt = (unsigned short*)d_ws;  // 32 MB used of >=64 MB ws

    cdist_kernel<<<dim3(4, 4, NB), 256, 0, stream>>>(X, Y, Wt);
    dtw_kernel<<<NB, 64, 0, stream>>>(Wt, out);
}

// Round 12
// 153.006 us; speedup vs baseline: 4.1173x; 1.0793x over previous
//
#include <hip/hip_runtime.h>
#include <math.h>

// Problem constants: B=64, N=512, d=64
#define NB 64
#define NN 512
#define ND 64

#define LOG2E 1.4426950408889634f
#define LN2   0.6931471805599453f
#define RING  12                      // prefetch ring depth (columns in flight)
#define NINF  __int_as_float(0xFF800000u)   // -inf

typedef __attribute__((ext_vector_type(8))) short  bf16x8;  // 8 bf16 in 4 VGPRs
typedef __attribute__((ext_vector_type(4))) float  f32x4;

// fp32 -> bf16 bits, round-to-nearest-even (inputs are finite)
static __device__ __forceinline__ unsigned short f2bf(float f) {
    unsigned u = __float_as_uint(f);
    u += 0x7FFFu + ((u >> 16) & 1u);
    return (unsigned short)(u >> 16);
}

// ---------------------------------------------------------------------------
// Kernel 0 (pack): X,Y (f32 row-major) -> bf16 in MFMA-fragment order, plus
// fp32 row norms. Slab layout: [b][tile=i/16][h=k/32] -> 512 elems where
// element ((q*16+lm)*8 + e) = val(row tile*16+lm, col h*32+q*8+e).
// A wave's fragment load in cdist becomes lane*8 -> 64 lanes x 16 B = 1 KB
// fully coalesced (the R11 cdist read 16 B/lane at 256 B stride - scattered).
// One thread per row: reads 256 B contiguous, writes 8 x 16 B chunks.
// ---------------------------------------------------------------------------
__global__ __launch_bounds__(256) void pack_kernel(const float* __restrict__ X,
                                                   const float* __restrict__ Y,
                                                   unsigned short* __restrict__ Xp,
                                                   unsigned short* __restrict__ Yp,
                                                   float* __restrict__ nx,
                                                   float* __restrict__ ny) {
    const int gid = blockIdx.x * 256 + threadIdx.x;   // row id, 0..NB*NN-1
    const float* src;
    unsigned short* dst;
    float* ndst;
    if (blockIdx.y == 0) { src = X + (size_t)gid * ND; dst = Xp; ndst = nx; }
    else                 { src = Y + (size_t)gid * ND; dst = Yp; ndst = ny; }

    float v[ND];
    float s = 0.f;
    #pragma unroll
    for (int k = 0; k < ND; k += 4) {
        float4 f = *(const float4*)(src + k);
        v[k] = f.x; v[k + 1] = f.y; v[k + 2] = f.z; v[k + 3] = f.w;
        s += f.x * f.x + f.y * f.y + f.z * f.z + f.w * f.w;   // same order as R11
    }
    ndst[gid] = s;

    const int b  = gid >> 9;
    const int i  = gid & 511;
    const int it = i >> 4;             // 16-row tile
    const int lm = i & 15;             // row within tile
    #pragma unroll
    for (int h = 0; h < 2; ++h) {
        #pragma unroll
        for (int q = 0; q < 4; ++q) {
            unsigned w[4];
            #pragma unroll
            for (int m = 0; m < 4; ++m) {
                const int c = h * 32 + q * 8 + 2 * m;
                w[m] = (unsigned)f2bf(v[c]) | ((unsigned)f2bf(v[c + 1]) << 16);
            }
            uint4 pkt; pkt.x = w[0]; pkt.y = w[1]; pkt.z = w[2]; pkt.w = w[3];
            *(uint4*)(dst + ((((size_t)b * 32 + it) * 2 + h) << 9)
                          + (size_t)(q * 16 + lm) * 8) = pkt;
        }
    }
}

// ---------------------------------------------------------------------------
// Kernel 1 (MFMA): Wt[b][j][i] = bf16( exp2(16 - log2e*||X[b][i]-Y[b][j]||) )
// All fragment loads now 1 KB coalesced from the packed slabs; norms read
// from the precomputed arrays. No LDS, no barrier. Numerics identical to R11
// (same bf16 RNE inputs, same MFMA, same epilogue).
// ---------------------------------------------------------------------------
__global__ __launch_bounds__(256) void cdist_kernel(const unsigned short* __restrict__ Xp,
                                                    const unsigned short* __restrict__ Yp,
                                                    const float* __restrict__ nx,
                                                    const float* __restrict__ ny,
                                                    unsigned short* __restrict__ Wt) {
    const int b  = blockIdx.z;
    const int ib = blockIdx.x * 128;   // i base (X rows)
    const int jb = blockIdx.y * 128;   // j base (Y rows)
    const int t  = threadIdx.x;

    const int wave = t >> 6;
    const int wi   = (wave & 1) * 64;   // i offset of this wave's 64x64 tile
    const int wj   = (wave >> 1) * 64;  // j offset
    const int lane = t & 63;
    const int lm   = lane & 15;
    const int quad = lane >> 4;

    f32x4 acc[4][4];
    #pragma unroll
    for (int mt = 0; mt < 4; ++mt)
        #pragma unroll
        for (int nt = 0; nt < 4; ++nt)
            acc[mt][nt] = (f32x4){0.f, 0.f, 0.f, 0.f};

    const int jt0 = (jb + wj) >> 4;    // Y tile base
    const int it0 = (ib + wi) >> 4;    // X tile base

    #pragma unroll
    for (int h = 0; h < 2; ++h) {
        bf16x8 Af[4], Bf[4];
        #pragma unroll
        for (int mt = 0; mt < 4; ++mt)   // A from Y tiles (m = j dim)
            Af[mt] = *(const bf16x8*)(Yp
                + ((((size_t)b * 32 + jt0 + mt) * 2 + h) << 9) + (size_t)lane * 8);
        #pragma unroll
        for (int nt = 0; nt < 4; ++nt)   // B from X tiles (n = i dim)
            Bf[nt] = *(const bf16x8*)(Xp
                + ((((size_t)b * 32 + it0 + nt) * 2 + h) << 9) + (size_t)lane * 8);
        #pragma unroll
        for (int mt = 0; mt < 4; ++mt)
            #pragma unroll
            for (int nt = 0; nt < 4; ++nt)
                acc[mt][nt] = __builtin_amdgcn_mfma_f32_16x16x32_bf16(
                    Af[mt], Bf[nt], acc[mt][nt], 0, 0, 0);
    }

    // --- epilogue: d2 = ny[j]+nx[i]-2*s; W = exp2(16 - LOG2E*sqrt(max(d2,0)))
    float nxv[4], nyv[4][4];
    #pragma unroll
    for (int nt = 0; nt < 4; ++nt)
        nxv[nt] = nx[(size_t)b * NN + ib + wi + nt * 16 + lm];
    #pragma unroll
    for (int mt = 0; mt < 4; ++mt)
        #pragma unroll
        for (int r = 0; r < 4; ++r)
            nyv[mt][r] = ny[(size_t)b * NN + jb + wj + mt * 16 + quad * 4 + r];

    #pragma unroll
    for (int mt = 0; mt < 4; ++mt) {
        const int j = jb + wj + mt * 16 + quad * 4;
        unsigned short* Drow = Wt + ((size_t)b * NN + j) * NN + ib + wi + lm;
        #pragma unroll
        for (int r = 0; r < 4; ++r) {
            #pragma unroll
            for (int nt = 0; nt < 4; ++nt) {
                float d2 = nyv[mt][r] + nxv[nt] - 2.0f * acc[mt][nt][r];
                float w  = __builtin_amdgcn_exp2f(16.0f - LOG2E * sqrtf(fmaxf(d2, 0.f)));
                Drow[(size_t)r * NN + nt * 16] = f2bf(w);
            }
        }
    }
}

// ---------------------------------------------------------------------------
// Kernel 2: soft-DTW DP — BYTE-IDENTICAL to R11's proven kernel.
// Exp-domain chain, branchless steady phase, full normalization every 2nd
// step, absolute log2-domain handoff.
// ---------------------------------------------------------------------------
static __device__ __forceinline__ void dtw_step(
    bool DOACT, bool DOGUARD, bool DOREN, bool DOCLAMP,
    int ss, int u, int t, const unsigned short* __restrict__ Wb, int ib,
    uint4* ring, float* L, float& diagHold, float& h, float& Otf)
{
    // lane t receives lane t-1's h (prev step); lane 0 gets -inf
    const float recvH = __int_as_float(__builtin_amdgcn_update_dpp(
        (int)0xFF800000, __float_as_int(h), 0x138 /*wave_shr:1*/, 0xf, 0xf, false));

    // activation: adopt neighbor's scale => up0 = 2^0 = 1, exact (R9-proven)
    if (DOACT) { if (ss == t && t > 0) Otf = -recvH; }

    const float up0   = __builtin_amdgcn_exp2f(fminf(recvH + Otf, 80.0f));
    const float diag0 = diagHold;              // 2^16 * F[ib][j-1], stored dom.
    diagHold = up0 * 65536.0f;                 // 2^16 * F[ib][j] for next step

    const int j = ss - t + 1;
    const uint4 c = ring[u];

    // refill slot u for step ss+RING (unconditional; overrun reads are dead)
    {
        int jn = j + RING;
        if (DOCLAMP) jn = jn < 1 ? 1 : jn;     // lower clamp (phase A only)
        ring[u] = *(const uint4*)(Wb + (size_t)(jn - 1) * NN + ib);
    }

    bool act = true;
    if (DOGUARD) act = (j >= 1) && (j <= NN);
    if (act) {
        float dd[8];                           // bf16 -> f32: shl/and, exact
        dd[0] = __uint_as_float(c.x << 16);
        dd[1] = __uint_as_float(c.x & 0xFFFF0000u);
        dd[2] = __uint_as_float(c.y << 16);
        dd[3] = __uint_as_float(c.y & 0xFFFF0000u);
        dd[4] = __uint_as_float(c.z << 16);
        dd[5] = __uint_as_float(c.z & 0xFFFF0000u);
        dd[6] = __uint_as_float(c.w << 16);
        dd[7] = __uint_as_float(c.w & 0xFFFF0000u);

        float pre[8], cc[8];
        pre[0] = diag0 + L[0];                 // diag0 already carries 2^16
        #pragma unroll
        for (int k = 1; k < 8; ++k)            // 2^16*diag + left (off-chain)
            pre[k] = fmaf(65536.0f, L[k - 1], L[k]);
        #pragma unroll
        for (int k = 0; k < 8; ++k) cc[k] = dd[k] * pre[k];
        float r = up0;
        #pragma unroll
        for (int k = 0; k < 8; ++k) {          // the only serial chain: 8 fma
            r = fmaf(dd[k], r, cc[k]);
            L[k] = r;
        }

        if (DOREN) {   // branchless FULL normalization: max(L) -> [1,2)
            float m8 = fmaxf(fmaxf(fmaxf(L[0], L[1]), fmaxf(L[2], L[3])),
                             fmaxf(fmaxf(L[4], L[5]), fmaxf(L[6], L[7])));
            const int   e  = (int)(__float_as_uint(m8) >> 23) - 127;
            const float sc = __uint_as_float((unsigned)(127 - e) << 23); // 2^-e
            #pragma unroll
            for (int k = 0; k < 8; ++k) L[k] *= sc;
            diagHold *= sc;
            Otf -= (float)e;                   // stored = F * 2^Ot invariant
        }

        // absolute log-domain handoff (invariant under renorm)
        h = __builtin_amdgcn_logf(L[7]) - Otf; // v_log_f32 = log2
    }
}

__global__ __launch_bounds__(64) void dtw_kernel(const unsigned short* __restrict__ Wt,
                                                 float* __restrict__ out) {
    const int b = blockIdx.x;
    const int t = threadIdx.x;                 // lane 0..63
    const unsigned short* __restrict__ Wb = Wt + (size_t)b * NN * NN;
    const int ib = 8 * t;                      // first owned row of W column

    float L[8];
    #pragma unroll
    for (int k = 0; k < 8; ++k) L[k] = 0.0f;   // F(inf) = 0 boundary

    float diagHold = (t == 0) ? 65536.0f : 0.0f;  // 2^16 * F[0][0] for lane 0
    float h        = NINF;                     // my bottom row, log2(F) domain
    float Otf      = 0.0f;                     // stored = F * 2^Ot

    // prefetch ring: slot u holds the 8 bf16 W values (one dwordx4) of the
    // column consumed at step ss == u (mod RING).
    uint4 ring[RING];
    #pragma unroll
    for (int u = 0; u < RING; ++u) {
        int col = u - t + 1;
        col = col < 1 ? 1 : col;               // clamp; dead if OOB
        ring[u] = *(const uint4*)(Wb + (size_t)(col - 1) * NN + ib);
    }

    // Phase A: guards + activation + lower clamp (ss 0..71)
    for (int sb = 0; sb < 72; sb += RING)
        #pragma unroll
        for (int u = 0; u < RING; ++u)
            dtw_step(true, true, (u & 1) == 1, true,
                     sb + u, u, t, Wb, ib, ring, L, diagHold, h, Otf);

    // Phase B: branchless hot loop (ss 72..503; all 64 lanes active)
    for (int sb = 72; sb < 504; sb += RING)
        #pragma unroll
        for (int u = 0; u < RING; ++u)
            dtw_step(false, false, (u & 1) == 1, false,
                     sb + u, u, t, Wb, ib, ring, L, diagHold, h, Otf);

    // Phase C: drain with j<=NN guard (ss 504..575)
    for (int sb = 504; sb < 576; sb += RING)
        #pragma unroll
        for (int u = 0; u < RING; ++u)
            dtw_step(false, true, (u & 1) == 1, false,
                     sb + u, u, t, Wb, ib, ring, L, diagHold, h, Otf);

    // R[N][N] = (16*1024 - log2 F) * ln2,  log2 F = h (lane 63, ss=574)
    if (t == 63) out[b] = (16384.0f - h) * LN2;
}

extern "C" void kernel_launch(void* const* d_in, const int* in_sizes, int n_in,
                              void* d_out, int out_size, void* d_ws, size_t ws_size,
                              hipStream_t stream) {
    const float* X = (const float*)d_in[0];
    const float* Y = (const float*)d_in[1];
    float* out = (float*)d_out;

    // workspace layout (ws >= 64 MB):
    //   [0, 32 MB)      Wt  : bf16 W matrix (dtw ring overrun reads land in
    //                         the pack slabs — dead values, in-bounds)
    //   [32, 36 MB)     Xp  : packed bf16 X fragments
    //   [36, 40 MB)     Yp  : packed bf16 Y fragments
    //   [40 MB, +128KB) nx  : fp32 row norms of X
    //   [+128KB,+256KB) ny  : fp32 row norms of Y
    char* ws = (char*)d_ws;
    unsigned short* Wt = (unsigned short*)(ws);
    unsigned short* Xp = (unsigned short*)(ws + (33554432));
    unsigned short* Yp = (unsigned short*)(ws + (33554432 + 4194304));
    float* nx = (float*)(ws + (33554432 + 2 * 4194304));
    float* ny = (float*)(ws + (33554432 + 2 * 4194304 + 131072));

    pack_kernel<<<dim3(NB * NN / 256, 2), 256, 0, stream>>>(X, Y, Xp, Yp, nx, ny);
    cdist_kernel<<<dim3(4, 4, NB), 256, 0, stream>>>(Xp, Yp, nx, ny, Wt);
    dtw_kernel<<<NB, 64, 0, stream>>>(Wt, out);
}